// Round 1
// baseline (1407.724 us; speedup 1.0000x reference)
//
#include <hip/hip_runtime.h>

#define N_SEQ 16384
#define LSEQ  512
#define VOCAB 32000
#define ES    32
#define HS    64
#define G3    192   // 3*HS
#define LDH   72    // padded f16 stride per m-row in LDS (2-way bank alias only)

typedef _Float16 v8h __attribute__((ext_vector_type(8)));
typedef float    v4f __attribute__((ext_vector_type(4)));

__device__ __forceinline__ float sig_fast(float x){
  // 1/(1+e^-x); e^-x via exp2. Large |x| saturates cleanly (inf -> rcp -> 0).
  float t = __builtin_amdgcn_exp2f(x * -1.4426950408889634f);
  return __builtin_amdgcn_rcpf(1.f + t);
}
__device__ __forceinline__ float tanh_fast(float x){
  // clamp so e^{-2x} stays finite (avoids (1-inf)*0 = NaN)
  x = fminf(fmaxf(x, -15.f), 15.f);
  float t = __builtin_amdgcn_exp2f(x * -2.8853900817779268f); // e^{-2x}
  return (1.f - t) * __builtin_amdgcn_rcpf(1.f + t);
}

// ---------------- K1: lengths + histogram (one wave per row) ----------------
__global__ __launch_bounds__(256) void k_len(const int* __restrict__ x,
                                             int* __restrict__ len,
                                             int* __restrict__ hist){
  int wid  = (blockIdx.x * 256 + threadIdx.x) >> 6;  // row id, grid sized exactly
  int lane = threadIdx.x & 63;
  const int* xr = x + (size_t)wid * LSEQ;
  int cnt = 0;
  #pragma unroll
  for (int j = 0; j < 8; ++j) cnt += (xr[lane + 64*j] != 0) ? 1 : 0;
  #pragma unroll
  for (int o = 32; o; o >>= 1) cnt += __shfl_down(cnt, o, 64);
  if (lane == 0){ len[wid] = cnt; atomicAdd(&hist[cnt], 1); }
}

// ---------------- K2: exclusive scan of hist[0..512] -> offs ----------------
__global__ __launch_bounds__(1024) void k_scan(const int* __restrict__ hist,
                                               int* __restrict__ offs){
  __shared__ int buf[1024];
  int i = threadIdx.x;
  buf[i] = (i < 513) ? hist[i] : 0;
  __syncthreads();
  for (int d = 1; d < 1024; d <<= 1){
    int v = (i >= d) ? buf[i - d] : 0;
    __syncthreads();
    buf[i] += v;
    __syncthreads();
  }
  if (i < 513) offs[i] = (i == 0) ? 0 : buf[i - 1];
}

// ---------------- K3: scatter seq ids sorted (ascending) by length ----------
__global__ __launch_bounds__(256) void k_scatter(const int* __restrict__ len,
                                                 int* __restrict__ offs,
                                                 int* __restrict__ perm){
  int i = blockIdx.x * 256 + threadIdx.x;
  int l = len[i];
  int pos = atomicAdd(&offs[l], 1);
  perm[pos] = i;
}

// ---------------- K4: gxtab[v][j] = emb[v]·wih[j] + bih[j] (+bhh[j] for r,z) -
__global__ __launch_bounds__(192) void k_gx(const float* __restrict__ emb,
                                            const float* __restrict__ wih,
                                            const float* __restrict__ bih,
                                            const float* __restrict__ bhh,
                                            float* __restrict__ gxtab){
  int v = blockIdx.x, j = threadIdx.x;
  const float* e = emb + (size_t)v * ES;
  const float* w = wih + (size_t)j * ES;
  // fold b_hh for r,z gates (they add outside the nonlinearity's r-scaling);
  // n-gate's b_hh must stay separate (it is scaled by r).
  float acc = bih[j] + (j < 2*HS ? bhh[j] : 0.f);
  #pragma unroll
  for (int k = 0; k < ES; ++k) acc = fmaf(e[k], w[k], acc);
  gxtab[(size_t)v * G3 + j] = acc;
}

// ---------------- K5: pack w_hh into f16 B-fragment layout ------------------
// B[k][n] = w_hh[n_glob][k];  frag (jt,kf): lane l holds k=(l>>4)*8+i+32*kf, n=l&15
__global__ __launch_bounds__(256) void k_wpack(const float* __restrict__ whh,
                                               _Float16* __restrict__ wpk){
  int tid = blockIdx.x * 256 + threadIdx.x;
  if (tid >= 24 * 64) return;
  int f = tid >> 6, l = tid & 63;
  int jt = f >> 1, kf = f & 1;
  #pragma unroll
  for (int i = 0; i < 8; ++i){
    int row = jt * 16 + (l & 15);           // w_hh row = output index j
    int col = kf * 32 + (l >> 4) * 8 + i;   // w_hh col = k
    wpk[(size_t)tid * 8 + i] = (_Float16)whh[row * HS + col];
  }
}

// ---------------- K6: the recurrence. One wave per 16 sorted sequences. -----
__global__ __launch_bounds__(256, 1) void k_gru(
    const int* __restrict__ x, const float* __restrict__ gxtab,
    const _Float16* __restrict__ wpk, const float* __restrict__ bhh,
    const int* __restrict__ perm, const int* __restrict__ len,
    float* __restrict__ out)
{
  __shared__ __align__(16) _Float16 hbuf_all[4][16 * LDH];
  int wib  = threadIdx.x >> 6;
  int wave = blockIdx.x * 4 + wib;       // 0..1023
  int lane = threadIdx.x & 63;
  int q = lane >> 4, c = lane & 15;
  _Float16* hb = hbuf_all[wib];

  // resident B fragments: 12 n-tiles x 2 k-fragments, 96 VGPRs
  v8h bf[12][2];
  #pragma unroll
  for (int jt = 0; jt < 12; ++jt)
    #pragma unroll
    for (int kf = 0; kf < 2; ++kf)
      bf[jt][kf] = *(const v8h*)(wpk + ((size_t)(jt*2 + kf)*64 + lane)*8);

  // my 4 sequences (C-layout rows m = q*4+r) and their lengths
  int sq[4], ln[4];
  #pragma unroll
  for (int r = 0; r < 4; ++r){
    int s = perm[wave * 16 + q*4 + r];
    sq[r] = s;
    ln[r] = len[s];
  }
  // b_hh for the n-gate, per my 4 u-slots (u = s*16 + c)
  float bn[4];
  #pragma unroll
  for (int s = 0; s < 4; ++s) bn[s] = bhh[2*HS + s*16 + c];

  float h[4][4];   // h[s][r] = h[m=q*4+r][u=s*16+c], fp32 master copy
  #pragma unroll
  for (int s = 0; s < 4; ++s)
    #pragma unroll
    for (int r = 0; r < 4; ++r) h[s][r] = 0.f;

  // zero the f16 h staging buffer (16*LDH = 1152 = 64*18)
  #pragma unroll
  for (int i = 0; i < 18; ++i) hb[lane * 18 + i] = (_Float16)0.f;

  int tmax = max(max(ln[0], ln[1]), max(ln[2], ln[3]));
  tmax = max(tmax, __shfl_xor(tmax, 16, 64));
  tmax = max(tmax, __shfl_xor(tmax, 32, 64));

  for (int t = 0; t < tmax; ++t){
    // tokens for my 4 rows (same addr across the 16 lanes of a quad -> L1 broadcast)
    int tk[4];
    #pragma unroll
    for (int r = 0; r < 4; ++r) tk[r] = x[(size_t)sq[r] * LSEQ + t];

    // gather gx in C-layout: gxv[jt][r] = gxtab[tok_m][jt*16 + c]
    float gxv[12][4];
    #pragma unroll
    for (int jt = 0; jt < 12; ++jt)
      #pragma unroll
      for (int r = 0; r < 4; ++r)
        gxv[jt][r] = gxtab[(size_t)tk[r] * G3 + jt*16 + c];

    // cross-lane LDS dependency within the wave: drain ds ops explicitly
    __asm__ volatile("s_waitcnt lgkmcnt(0)" ::: "memory");
    // A-fragments: A[m=lane&15][k=q*8+i(+32)]  (m120-verified layout)
    v8h a0 = *(const v8h*)(hb + c*LDH + q*8);
    v8h a1 = *(const v8h*)(hb + c*LDH + 32 + q*8);

    v4f D[12];
    #pragma unroll
    for (int jt = 0; jt < 12; ++jt){
      v4f z4 = {0.f, 0.f, 0.f, 0.f};
      z4    = __builtin_amdgcn_mfma_f32_16x16x32_f16(a0, bf[jt][0], z4, 0, 0, 0);
      D[jt] = __builtin_amdgcn_mfma_f32_16x16x32_f16(a1, bf[jt][1], z4, 0, 0, 0);
    }

    // gates: lane-local triplets. D[s]=r-part, D[s+4]=z-part, D[s+8]=n-part.
    #pragma unroll
    for (int s = 0; s < 4; ++s){
      #pragma unroll
      for (int r = 0; r < 4; ++r){
        float rg   = sig_fast(gxv[s][r]   + D[s][r]);
        float zg   = sig_fast(gxv[s+4][r] + D[s+4][r]);
        float hn   = D[s+8][r] + bn[s];
        float ng   = tanh_fast(gxv[s+8][r] + rg * hn);
        float hnew = ng + zg * (h[s][r] - ng);
        h[s][r]    = (t < ln[r]) ? hnew : h[s][r];
      }
    }

    // stage h as f16 for the next step's A-fragments (in-order per-wave ds ops
    // make the read-then-write within this iteration WAR-safe)
    #pragma unroll
    for (int s = 0; s < 4; ++s)
      #pragma unroll
      for (int r = 0; r < 4; ++r)
        hb[(q*4 + r)*LDH + s*16 + c] = (_Float16)h[s][r];
  }

  #pragma unroll
  for (int s = 0; s < 4; ++s)
    #pragma unroll
    for (int r = 0; r < 4; ++r)
      out[(size_t)sq[r] * HS + s*16 + c] = h[s][r];
}

extern "C" void kernel_launch(void* const* d_in, const int* in_sizes, int n_in,
                              void* d_out, int out_size, void* d_ws, size_t ws_size,
                              hipStream_t stream){
  const int*   x   = (const int*)  d_in[0];
  const float* emb = (const float*)d_in[1];
  const float* wih = (const float*)d_in[2];
  const float* whh = (const float*)d_in[3];
  const float* bih = (const float*)d_in[4];
  const float* bhh = (const float*)d_in[5];
  float* out = (float*)d_out;

  // workspace layout (~24.8 MB)
  char* ws = (char*)d_ws;
  size_t off = 0;
  float* gxtab = (float*)(ws + off);      off += (size_t)VOCAB * G3 * sizeof(float);
  _Float16* wpk = (_Float16*)(ws + off);  off += (size_t)24 * 64 * 8 * sizeof(_Float16);
  off = (off + 255) & ~(size_t)255;
  int* len  = (int*)(ws + off);           off += (size_t)N_SEQ * sizeof(int);
  int* perm = (int*)(ws + off);           off += (size_t)N_SEQ * sizeof(int);
  int* hist = (int*)(ws + off);           off += 513 * sizeof(int);
  off = (off + 255) & ~(size_t)255;
  int* offs = (int*)(ws + off);           off += 513 * sizeof(int);

  hipMemsetAsync(hist, 0, 513 * sizeof(int), stream);
  k_len    <<<N_SEQ / 4,   256, 0, stream>>>(x, len, hist);
  k_scan   <<<1,          1024, 0, stream>>>(hist, offs);
  k_scatter<<<N_SEQ / 256, 256, 0, stream>>>(len, offs, perm);
  k_gx     <<<VOCAB,       192, 0, stream>>>(emb, wih, bih, bhh, gxtab);
  k_wpack  <<<6,           256, 0, stream>>>(whh, wpk);
  k_gru    <<<N_SEQ / 64,  256, 0, stream>>>(x, gxtab, wpk, bhh, perm, len, out);
}

// Round 2
// 814.788 us; speedup vs baseline: 1.7277x; 1.7277x over previous
//
#include <hip/hip_runtime.h>

#define N_SEQ 16384
#define LSEQ  512
#define VOCAB 32000
#define ES    32
#define HS    64
#define G3    192   // 3*HS
#define LDH   72    // padded f16 stride per m-row in LDS (2-way bank alias only)

typedef _Float16 v8h __attribute__((ext_vector_type(8)));
typedef float    v4f __attribute__((ext_vector_type(4)));

__device__ __forceinline__ float sig_fast(float x){
  float t = __builtin_amdgcn_exp2f(x * -1.4426950408889634f);
  return __builtin_amdgcn_rcpf(1.f + t);
}
__device__ __forceinline__ float tanh_fast(float x){
  x = fminf(fmaxf(x, -15.f), 15.f);
  float t = __builtin_amdgcn_exp2f(x * -2.8853900817779268f); // e^{-2x}
  return (1.f - t) * __builtin_amdgcn_rcpf(1.f + t);
}

// ---------------- K1: lengths + histogram (one wave per row) ----------------
__global__ __launch_bounds__(256) void k_len(const int* __restrict__ x,
                                             int* __restrict__ len,
                                             int* __restrict__ hist){
  int wid  = (blockIdx.x * 256 + threadIdx.x) >> 6;
  int lane = threadIdx.x & 63;
  const int* xr = x + (size_t)wid * LSEQ;
  int cnt = 0;
  #pragma unroll
  for (int j = 0; j < 8; ++j) cnt += (xr[lane + 64*j] != 0) ? 1 : 0;
  #pragma unroll
  for (int o = 32; o; o >>= 1) cnt += __shfl_down(cnt, o, 64);
  if (lane == 0){ len[wid] = cnt; atomicAdd(&hist[cnt], 1); }
}

// ---------------- K2: exclusive scan of hist[0..512] -> offs ----------------
__global__ __launch_bounds__(1024) void k_scan(const int* __restrict__ hist,
                                               int* __restrict__ offs){
  __shared__ int buf[1024];
  int i = threadIdx.x;
  buf[i] = (i < 513) ? hist[i] : 0;
  __syncthreads();
  for (int d = 1; d < 1024; d <<= 1){
    int v = (i >= d) ? buf[i - d] : 0;
    __syncthreads();
    buf[i] += v;
    __syncthreads();
  }
  if (i < 513) offs[i] = (i == 0) ? 0 : buf[i - 1];
}

// ---------------- K3: scatter seq ids sorted (ascending) by length ----------
__global__ __launch_bounds__(256) void k_scatter(const int* __restrict__ len,
                                                 int* __restrict__ offs,
                                                 int* __restrict__ perm){
  int i = blockIdx.x * 256 + threadIdx.x;
  int l = len[i];
  int pos = atomicAdd(&offs[l], 1);
  perm[pos] = i;
}

// ---------------- K4: gxtab, c-major row layout --------------------------
// gate index j = jt*16 + c  ->  stored at v*192 + c*12 + jt, so one lane's
// 12 per-token gate values (fixed c, all jt) are 3 contiguous float4s.
__global__ __launch_bounds__(192) void k_gx(const float* __restrict__ emb,
                                            const float* __restrict__ wih,
                                            const float* __restrict__ bih,
                                            const float* __restrict__ bhh,
                                            float* __restrict__ gxtab){
  int v = blockIdx.x, j = threadIdx.x;
  const float* e = emb + (size_t)v * ES;
  const float* w = wih + (size_t)j * ES;
  // fold b_hh for r,z gates; n-gate's b_hh stays separate (scaled by r).
  float acc = bih[j] + (j < 2*HS ? bhh[j] : 0.f);
  #pragma unroll
  for (int k = 0; k < ES; ++k) acc = fmaf(e[k], w[k], acc);
  int jt = j >> 4, c = j & 15;
  gxtab[(size_t)v * G3 + c * 12 + jt] = acc;
}

// ---------------- K5: pack w_hh into f16 B-fragment layout ------------------
__global__ __launch_bounds__(256) void k_wpack(const float* __restrict__ whh,
                                               _Float16* __restrict__ wpk){
  int tid = blockIdx.x * 256 + threadIdx.x;
  if (tid >= 24 * 64) return;
  int f = tid >> 6, l = tid & 63;
  int jt = f >> 1, kf = f & 1;
  #pragma unroll
  for (int i = 0; i < 8; ++i){
    int row = jt * 16 + (l & 15);           // w_hh row = output index j
    int col = kf * 32 + (l >> 4) * 8 + i;   // w_hh col = k
    wpk[(size_t)tid * 8 + i] = (_Float16)whh[row * HS + col];
  }
}

// ---------------- K6: the recurrence, software-pipelined --------------------
__global__ __launch_bounds__(256, 1) void k_gru(
    const int* __restrict__ x, const float* __restrict__ gxtab,
    const _Float16* __restrict__ wpk, const float* __restrict__ bhh,
    const int* __restrict__ perm, const int* __restrict__ len,
    float* __restrict__ out)
{
  __shared__ __align__(16) _Float16 hbuf_all[4][16 * LDH];
  int wib  = threadIdx.x >> 6;
  int wave = blockIdx.x * 4 + wib;
  int lane = threadIdx.x & 63;
  int q = lane >> 4, c = lane & 15;
  _Float16* hb = hbuf_all[wib];

  // resident B fragments: 12 n-tiles x 2 k-fragments, 96 VGPRs
  v8h bf[12][2];
  #pragma unroll
  for (int jt = 0; jt < 12; ++jt)
    #pragma unroll
    for (int kf = 0; kf < 2; ++kf)
      bf[jt][kf] = *(const v8h*)(wpk + ((size_t)(jt*2 + kf)*64 + lane)*8);

  int sq[4], ln[4];
  #pragma unroll
  for (int r = 0; r < 4; ++r){
    int s = perm[wave * 16 + q*4 + r];
    sq[r] = s;
    ln[r] = len[s];
  }
  float bn[4];
  #pragma unroll
  for (int s = 0; s < 4; ++s) bn[s] = bhh[2*HS + s*16 + c];

  float h[4][4];   // h[s][r] = h[m=q*4+r][u=s*16+c], fp32 master copy
  #pragma unroll
  for (int s = 0; s < 4; ++s)
    #pragma unroll
    for (int r = 0; r < 4; ++r) h[s][r] = 0.f;

  #pragma unroll
  for (int i = 0; i < 18; ++i) hb[lane * 18 + i] = (_Float16)0.f;

  int tmax = max(max(ln[0], ln[1]), max(ln[2], ln[3]));
  tmax = max(tmax, __shfl_xor(tmax, 16, 64));
  tmax = max(tmax, __shfl_xor(tmax, 32, 64));

  // ---- pipeline prologue: gx[0] in ga, tokens[1] in tkc ----
  v4f ga[4][3], gb[4][3];   // gx double buffer: [r][i], i = gate group (r/z/n)
  int tkc[4], tkn[4];       // tokens for t+1 (consumed for gx prefetch), t+2
  {
    int t0k[4];
    #pragma unroll
    for (int r = 0; r < 4; ++r) t0k[r] = x[(size_t)sq[r] * LSEQ + 0];
    #pragma unroll
    for (int r = 0; r < 4; ++r){
      const v4f* p = (const v4f*)(gxtab + (size_t)t0k[r] * G3 + c * 12);
      #pragma unroll
      for (int i = 0; i < 3; ++i) ga[r][i] = p[i];
    }
    #pragma unroll
    for (int r = 0; r < 4; ++r) tkc[r] = x[(size_t)sq[r] * LSEQ + 1];
  }

  #define GRU_STEP(GC, GN, TKC_, TKN_)                                         \
  {                                                                            \
    /* prefetch gx for t+1 (tokens already resident) */                        \
    _Pragma("unroll")                                                          \
    for (int r = 0; r < 4; ++r){                                               \
      const v4f* p = (const v4f*)(gxtab + (size_t)TKC_[r] * G3 + c * 12);      \
      _Pragma("unroll")                                                        \
      for (int i = 0; i < 3; ++i) GN[r][i] = p[i];                             \
    }                                                                          \
    /* prefetch tokens for t+2 */                                              \
    int t2 = min(t + 2, LSEQ - 1);                                             \
    _Pragma("unroll")                                                          \
    for (int r = 0; r < 4; ++r) TKN_[r] = x[(size_t)sq[r] * LSEQ + t2];        \
    /* cross-lane LDS dep: drain previous step's h writes */                   \
    __asm__ volatile("s_waitcnt lgkmcnt(0)" ::: "memory");                     \
    v8h a0 = *(const v8h*)(hb + c*LDH + q*8);                                  \
    v8h a1 = *(const v8h*)(hb + c*LDH + 32 + q*8);                             \
    v4f D[12];                                                                 \
    _Pragma("unroll")                                                          \
    for (int jt = 0; jt < 12; ++jt){                                           \
      v4f z4 = {0.f, 0.f, 0.f, 0.f};                                           \
      z4    = __builtin_amdgcn_mfma_f32_16x16x32_f16(a0, bf[jt][0], z4, 0,0,0);\
      D[jt] = __builtin_amdgcn_mfma_f32_16x16x32_f16(a1, bf[jt][1], z4, 0,0,0);\
    }                                                                          \
    _Pragma("unroll")                                                          \
    for (int s = 0; s < 4; ++s){                                               \
      _Pragma("unroll")                                                        \
      for (int r = 0; r < 4; ++r){                                             \
        float rg   = sig_fast(GC[r][0][s] + D[s][r]);                          \
        float zg   = sig_fast(GC[r][1][s] + D[s+4][r]);                        \
        float hn   = D[s+8][r] + bn[s];                                        \
        float ng   = tanh_fast(GC[r][2][s] + rg * hn);                         \
        float hnew = ng + zg * (h[s][r] - ng);                                 \
        h[s][r]    = (t < ln[r]) ? hnew : h[s][r];                             \
      }                                                                        \
    }                                                                          \
    _Pragma("unroll")                                                          \
    for (int s = 0; s < 4; ++s)                                                \
      _Pragma("unroll")                                                        \
      for (int r = 0; r < 4; ++r)                                              \
        hb[(q*4 + r)*LDH + s*16 + c] = (_Float16)h[s][r];                      \
  }

  // unroll-by-2 main loop with ping-pong buffers
  int t = 0;
  for (; t + 1 < tmax; ){
    GRU_STEP(ga, gb, tkc, tkn); ++t;
    GRU_STEP(gb, ga, tkn, tkc); ++t;
  }
  if (t < tmax){
    GRU_STEP(ga, gb, tkc, tkn); ++t;
  }
  #undef GRU_STEP

  #pragma unroll
  for (int s = 0; s < 4; ++s)
    #pragma unroll
    for (int r = 0; r < 4; ++r)
      out[(size_t)sq[r] * HS + s*16 + c] = h[s][r];
}

extern "C" void kernel_launch(void* const* d_in, const int* in_sizes, int n_in,
                              void* d_out, int out_size, void* d_ws, size_t ws_size,
                              hipStream_t stream){
  const int*   x   = (const int*)  d_in[0];
  const float* emb = (const float*)d_in[1];
  const float* wih = (const float*)d_in[2];
  const float* whh = (const float*)d_in[3];
  const float* bih = (const float*)d_in[4];
  const float* bhh = (const float*)d_in[5];
  float* out = (float*)d_out;

  char* ws = (char*)d_ws;
  size_t off = 0;
  float* gxtab = (float*)(ws + off);      off += (size_t)VOCAB * G3 * sizeof(float);
  _Float16* wpk = (_Float16*)(ws + off);  off += (size_t)24 * 64 * 8 * sizeof(_Float16);
  off = (off + 255) & ~(size_t)255;
  int* len  = (int*)(ws + off);           off += (size_t)N_SEQ * sizeof(int);
  int* perm = (int*)(ws + off);           off += (size_t)N_SEQ * sizeof(int);
  int* hist = (int*)(ws + off);           off += 513 * sizeof(int);
  off = (off + 255) & ~(size_t)255;
  int* offs = (int*)(ws + off);           off += 513 * sizeof(int);

  hipMemsetAsync(hist, 0, 513 * sizeof(int), stream);
  k_len    <<<N_SEQ / 4,   256, 0, stream>>>(x, len, hist);
  k_scan   <<<1,          1024, 0, stream>>>(hist, offs);
  k_scatter<<<N_SEQ / 256, 256, 0, stream>>>(len, offs, perm);
  k_gx     <<<VOCAB,       192, 0, stream>>>(emb, wih, bih, bhh, gxtab);
  k_wpack  <<<6,           256, 0, stream>>>(whh, wpk);
  k_gru    <<<N_SEQ / 64,  256, 0, stream>>>(x, gxtab, wpk, bhh, perm, len, out);
}

// Round 3
// 733.527 us; speedup vs baseline: 1.9191x; 1.1108x over previous
//
#include <hip/hip_runtime.h>

#define N_SEQ 16384
#define LSEQ  512
#define VOCAB 32000
#define ES    32
#define HS    64
#define G3    192   // 3*HS
#define LDH   72    // padded f16 stride per m-row in LDS

typedef _Float16 v8h __attribute__((ext_vector_type(8)));
typedef float    v4f __attribute__((ext_vector_type(4)));
typedef float    v2f __attribute__((ext_vector_type(2)));

__device__ __forceinline__ float sig_fast(float x){
  float t = __builtin_amdgcn_exp2f(x * -1.4426950408889634f);
  return __builtin_amdgcn_rcpf(1.f + t);
}
__device__ __forceinline__ float tanh_fast(float x){
  x = fminf(fmaxf(x, -15.f), 15.f);
  float t = __builtin_amdgcn_exp2f(x * -2.8853900817779268f); // e^{-2x}
  return (1.f - t) * __builtin_amdgcn_rcpf(1.f + t);
}

// ---------------- K1: lengths + histogram (one wave per row) ----------------
__global__ __launch_bounds__(256) void k_len(const int* __restrict__ x,
                                             int* __restrict__ len,
                                             int* __restrict__ hist){
  int wid  = (blockIdx.x * 256 + threadIdx.x) >> 6;
  int lane = threadIdx.x & 63;
  const int* xr = x + (size_t)wid * LSEQ;
  int cnt = 0;
  #pragma unroll
  for (int j = 0; j < 8; ++j) cnt += (xr[lane + 64*j] != 0) ? 1 : 0;
  #pragma unroll
  for (int o = 32; o; o >>= 1) cnt += __shfl_down(cnt, o, 64);
  if (lane == 0){ len[wid] = cnt; atomicAdd(&hist[cnt], 1); }
}

// ---------------- K2: exclusive scan of hist[0..512] -> offs ----------------
__global__ __launch_bounds__(1024) void k_scan(const int* __restrict__ hist,
                                               int* __restrict__ offs){
  __shared__ int buf[1024];
  int i = threadIdx.x;
  buf[i] = (i < 513) ? hist[i] : 0;
  __syncthreads();
  for (int d = 1; d < 1024; d <<= 1){
    int v = (i >= d) ? buf[i - d] : 0;
    __syncthreads();
    buf[i] += v;
    __syncthreads();
  }
  if (i < 513) offs[i] = (i == 0) ? 0 : buf[i - 1];
}

// ---------------- K3: scatter seq ids sorted (ascending) by length ----------
__global__ __launch_bounds__(256) void k_scatter(const int* __restrict__ len,
                                                 int* __restrict__ offs,
                                                 int* __restrict__ perm){
  int i = blockIdx.x * 256 + threadIdx.x;
  int l = len[i];
  int pos = atomicAdd(&offs[l], 1);
  perm[pos] = i;
}

// ---------------- K4: gxtab, layout [v][half][c][6] -------------------------
// j = g*64 + half*32 + lt*16 + c  ->  gxtab[v*192 + (half*16+c)*6 + g*2 + lt]
// so one lane's 6 per-token gate values are 3 contiguous float2s (8B aligned).
__global__ __launch_bounds__(192) void k_gx(const float* __restrict__ emb,
                                            const float* __restrict__ wih,
                                            const float* __restrict__ bih,
                                            const float* __restrict__ bhh,
                                            float* __restrict__ gxtab){
  int v = blockIdx.x, j = threadIdx.x;
  const float* e = emb + (size_t)v * ES;
  const float* w = wih + (size_t)j * ES;
  // fold b_hh for r,z gates; n-gate's b_hh stays separate (scaled by r).
  float acc = bih[j] + (j < 2*HS ? bhh[j] : 0.f);
  #pragma unroll
  for (int k = 0; k < ES; ++k) acc = fmaf(e[k], w[k], acc);
  int g = j >> 6, u = j & 63;
  int half = u >> 5, lt = (u >> 4) & 1, c = u & 15;
  gxtab[(size_t)v * G3 + (half*16 + c)*6 + g*2 + lt] = acc;
}

// ---------------- K5: pack w_hh into f16 B-fragment layout ------------------
__global__ __launch_bounds__(256) void k_wpack(const float* __restrict__ whh,
                                               _Float16* __restrict__ wpk){
  int tid = blockIdx.x * 256 + threadIdx.x;
  if (tid >= 24 * 64) return;
  int f = tid >> 6, l = tid & 63;
  int jt = f >> 1, kf = f & 1;
  #pragma unroll
  for (int i = 0; i < 8; ++i){
    int row = jt * 16 + (l & 15);           // w_hh row = output index j
    int col = kf * 32 + (l >> 4) * 8 + i;   // w_hh col = k
    wpk[(size_t)tid * 8 + i] = (_Float16)whh[row * HS + col];
  }
}

// ---------------- K6: recurrence. Block = 2 waves, u-dim split across them. -
// Wave `half` owns hidden units u in [32*half, 32*half+32): computes their
// r/z/n gates (6 j-tiles, full K=64) and h updates. Coupling: ping-pong LDS
// h buffer + one __syncthreads per step. 2048 waves -> 2 waves/SIMD.
__global__ __launch_bounds__(128, 2) void k_gru(
    const int* __restrict__ x, const float* __restrict__ gxtab,
    const _Float16* __restrict__ wpk, const float* __restrict__ bhh,
    const int* __restrict__ perm, const int* __restrict__ len,
    float* __restrict__ out)
{
  __shared__ __align__(16) _Float16 hb[2][16 * LDH];
  int half = threadIdx.x >> 6;           // which u-half this wave owns
  int blk  = blockIdx.x;                 // 16 sorted seqs per block
  int lane = threadIdx.x & 63;
  int q = lane >> 4, c = lane & 15;

  // resident B fragments: 3 gates x 2 local tiles x 2 k-frags = 48 VGPRs
  v8h bf[3][2][2];
  #pragma unroll
  for (int g = 0; g < 3; ++g)
    #pragma unroll
    for (int lt = 0; lt < 2; ++lt)
      #pragma unroll
      for (int kf = 0; kf < 2; ++kf){
        int f = (g*4 + half*2 + lt)*2 + kf;
        bf[g][lt][kf] = *(const v8h*)(wpk + ((size_t)f*64 + lane)*8);
      }

  int sq[4], ln[4];
  #pragma unroll
  for (int r = 0; r < 4; ++r){
    int s = perm[blk * 16 + q*4 + r];
    sq[r] = s;
    ln[r] = len[s];
  }
  float bn[2];
  #pragma unroll
  for (int lt = 0; lt < 2; ++lt) bn[lt] = bhh[2*HS + half*32 + lt*16 + c];

  float h[2][4];   // h[lt][r]: unit u = half*32+lt*16+c of seq m = q*4+r
  #pragma unroll
  for (int lt = 0; lt < 2; ++lt)
    #pragma unroll
    for (int r = 0; r < 4; ++r) h[lt][r] = 0.f;

  for (int i = threadIdx.x; i < 16*LDH; i += 128) hb[0][i] = (_Float16)0.f;
  __syncthreads();

  int tmax = max(max(ln[0], ln[1]), max(ln[2], ln[3]));
  tmax = max(tmax, __shfl_xor(tmax, 16, 64));
  tmax = max(tmax, __shfl_xor(tmax, 32, 64));

  // gx double buffer: [r][g] float2, element .x/.y selects lt
  v2f ga[4][3], gb[4][3];
  int tkc[4], tkn[4];
  {
    int t0k[4];
    #pragma unroll
    for (int r = 0; r < 4; ++r) t0k[r] = x[(size_t)sq[r] * LSEQ + 0];
    #pragma unroll
    for (int r = 0; r < 4; ++r){
      const v2f* p = (const v2f*)(gxtab + (size_t)t0k[r] * G3 + (half*16 + c)*6);
      #pragma unroll
      for (int g = 0; g < 3; ++g) ga[r][g] = p[g];
    }
    #pragma unroll
    for (int r = 0; r < 4; ++r) tkc[r] = x[(size_t)sq[r] * LSEQ + 1];
  }

  #define GRU_STEP(GC, GN, TKC_, TKN_, RB, WB)                                 \
  {                                                                            \
    _Pragma("unroll")                                                          \
    for (int r = 0; r < 4; ++r){                                               \
      const v2f* p = (const v2f*)(gxtab + (size_t)TKC_[r] * G3 + (half*16+c)*6);\
      _Pragma("unroll")                                                        \
      for (int g = 0; g < 3; ++g) GN[r][g] = p[g];                             \
    }                                                                          \
    int t2 = min(t + 2, LSEQ - 1);                                             \
    _Pragma("unroll")                                                          \
    for (int r = 0; r < 4; ++r) TKN_[r] = x[(size_t)sq[r] * LSEQ + t2];        \
    v8h a0 = *(const v8h*)(&hb[RB][c*LDH + q*8]);                              \
    v8h a1 = *(const v8h*)(&hb[RB][c*LDH + 32 + q*8]);                         \
    v4f D[3][2];                                                               \
    _Pragma("unroll")                                                          \
    for (int g = 0; g < 3; ++g)                                                \
      _Pragma("unroll")                                                        \
      for (int lt = 0; lt < 2; ++lt){                                          \
        v4f z4;                                                                \
        float bi = (g == 2) ? bn[lt] : 0.f;                                    \
        z4[0] = bi; z4[1] = bi; z4[2] = bi; z4[3] = bi;                        \
        z4        = __builtin_amdgcn_mfma_f32_16x16x32_f16(a0, bf[g][lt][0], z4, 0,0,0); \
        D[g][lt]  = __builtin_amdgcn_mfma_f32_16x16x32_f16(a1, bf[g][lt][1], z4, 0,0,0); \
      }                                                                        \
    _Pragma("unroll")                                                          \
    for (int lt = 0; lt < 2; ++lt){                                            \
      _Pragma("unroll")                                                        \
      for (int r = 0; r < 4; ++r){                                             \
        float rg   = sig_fast(GC[r][0][lt] + D[0][lt][r]);                     \
        float zg   = sig_fast(GC[r][1][lt] + D[1][lt][r]);                     \
        float ng   = tanh_fast(GC[r][2][lt] + rg * D[2][lt][r]);               \
        float hnew = ng + zg * (h[lt][r] - ng);                                \
        h[lt][r]   = (t < ln[r]) ? hnew : h[lt][r];                            \
      }                                                                        \
    }                                                                          \
    _Pragma("unroll")                                                          \
    for (int lt = 0; lt < 2; ++lt)                                             \
      _Pragma("unroll")                                                        \
      for (int r = 0; r < 4; ++r)                                              \
        hb[WB][(q*4 + r)*LDH + half*32 + lt*16 + c] = (_Float16)h[lt][r];      \
    __syncthreads();                                                           \
  }

  int t = 0;
  for (; t + 1 < tmax; ){
    GRU_STEP(ga, gb, tkc, tkn, 0, 1); ++t;
    GRU_STEP(gb, ga, tkn, tkc, 1, 0); ++t;
  }
  if (t < tmax){
    GRU_STEP(ga, gb, tkc, tkn, 0, 1); ++t;
  }
  #undef GRU_STEP

  #pragma unroll
  for (int lt = 0; lt < 2; ++lt)
    #pragma unroll
    for (int r = 0; r < 4; ++r)
      out[(size_t)sq[r] * HS + half*32 + lt*16 + c] = h[lt][r];
}

extern "C" void kernel_launch(void* const* d_in, const int* in_sizes, int n_in,
                              void* d_out, int out_size, void* d_ws, size_t ws_size,
                              hipStream_t stream){
  const int*   x   = (const int*)  d_in[0];
  const float* emb = (const float*)d_in[1];
  const float* wih = (const float*)d_in[2];
  const float* whh = (const float*)d_in[3];
  const float* bih = (const float*)d_in[4];
  const float* bhh = (const float*)d_in[5];
  float* out = (float*)d_out;

  char* ws = (char*)d_ws;
  size_t off = 0;
  float* gxtab = (float*)(ws + off);      off += (size_t)VOCAB * G3 * sizeof(float);
  _Float16* wpk = (_Float16*)(ws + off);  off += (size_t)24 * 64 * 8 * sizeof(_Float16);
  off = (off + 255) & ~(size_t)255;
  int* len  = (int*)(ws + off);           off += (size_t)N_SEQ * sizeof(int);
  int* perm = (int*)(ws + off);           off += (size_t)N_SEQ * sizeof(int);
  int* hist = (int*)(ws + off);           off += 513 * sizeof(int);
  off = (off + 255) & ~(size_t)255;
  int* offs = (int*)(ws + off);           off += 513 * sizeof(int);

  hipMemsetAsync(hist, 0, 513 * sizeof(int), stream);
  k_len    <<<N_SEQ / 4,   256, 0, stream>>>(x, len, hist);
  k_scan   <<<1,          1024, 0, stream>>>(hist, offs);
  k_scatter<<<N_SEQ / 256, 256, 0, stream>>>(len, offs, perm);
  k_gx     <<<VOCAB,       192, 0, stream>>>(emb, wih, bih, bhh, gxtab);
  k_wpack  <<<6,           256, 0, stream>>>(whh, wpk);
  k_gru    <<<N_SEQ / 16,  128, 0, stream>>>(x, gxtab, wpk, bhh, perm, len, out);
}

// Round 5
// 571.414 us; speedup vs baseline: 2.4636x; 1.2837x over previous
//
#include <hip/hip_runtime.h>

#define N_SEQ 16384
#define LSEQ  512
#define VOCAB 32000
#define ES    32
#define HS    64
#define LDH   72    // padded f16 stride per m-row in LDS

typedef _Float16 v8h __attribute__((ext_vector_type(8)));
typedef float    v4f __attribute__((ext_vector_type(4)));

__device__ __forceinline__ float sig_fast(float x){
  float t = __builtin_amdgcn_exp2f(x * -1.4426950408889634f);
  return __builtin_amdgcn_rcpf(1.f + t);
}
__device__ __forceinline__ float tanh_fast(float x){
  x = fminf(fmaxf(x, -15.f), 15.f);
  float t = __builtin_amdgcn_exp2f(x * -2.8853900817779268f); // e^{-2x}
  return (1.f - t) * __builtin_amdgcn_rcpf(1.f + t);
}

// ---------------- K1: lengths + histogram (one wave per row) ----------------
__global__ __launch_bounds__(256) void k_len(const int* __restrict__ x,
                                             int* __restrict__ len,
                                             int* __restrict__ hist){
  int wid  = (blockIdx.x * 256 + threadIdx.x) >> 6;
  int lane = threadIdx.x & 63;
  const int* xr = x + (size_t)wid * LSEQ;
  int cnt = 0;
  #pragma unroll
  for (int j = 0; j < 8; ++j) cnt += (xr[lane + 64*j] != 0) ? 1 : 0;
  #pragma unroll
  for (int o = 32; o; o >>= 1) cnt += __shfl_down(cnt, o, 64);
  if (lane == 0){ len[wid] = cnt; atomicAdd(&hist[cnt], 1); }
}

// ---------------- K2: exclusive scan of hist[0..512] -> offs ----------------
__global__ __launch_bounds__(1024) void k_scan(const int* __restrict__ hist,
                                               int* __restrict__ offs){
  __shared__ int buf[1024];
  int i = threadIdx.x;
  buf[i] = (i < 513) ? hist[i] : 0;
  __syncthreads();
  for (int d = 1; d < 1024; d <<= 1){
    int v = (i >= d) ? buf[i - d] : 0;
    __syncthreads();
    buf[i] += v;
    __syncthreads();
  }
  if (i < 513) offs[i] = (i == 0) ? 0 : buf[i - 1];
}

// ---------------- K3: scatter seq ids sorted (ascending) by length ----------
__global__ __launch_bounds__(256) void k_scatter(const int* __restrict__ len,
                                                 int* __restrict__ offs,
                                                 int* __restrict__ perm){
  int i = blockIdx.x * 256 + threadIdx.x;
  int l = len[i];
  int pos = atomicAdd(&offs[l], 1);
  perm[pos] = i;
}

// ---------------- K4: embedding f32 -> f16 (row-contiguous, 64B/row) --------
__global__ __launch_bounds__(256) void k_emb(const float* __restrict__ emb,
                                             _Float16* __restrict__ ef){
  int i = blockIdx.x * 256 + threadIdx.x;
  if (i < VOCAB * ES) ef[i] = (_Float16)emb[i];
}

// ---------------- K5a: pack w_hh into f16 B-fragment layout (K=64: 2 frags) -
__global__ __launch_bounds__(256) void k_wpack(const float* __restrict__ whh,
                                               _Float16* __restrict__ wpk){
  int tid = blockIdx.x * 256 + threadIdx.x;
  if (tid >= 24 * 64) return;
  int f = tid >> 6, l = tid & 63;
  int jt = f >> 1, kf = f & 1;
  #pragma unroll
  for (int i = 0; i < 8; ++i){
    int row = jt * 16 + (l & 15);           // w_hh row = output index j
    int col = kf * 32 + (l >> 4) * 8 + i;   // w_hh col = k
    wpk[(size_t)tid * 8 + i] = (_Float16)whh[row * HS + col];
  }
}

// ---------------- K5b: pack w_ih into f16 B-fragment layout (K=32: 1 frag) --
__global__ __launch_bounds__(256) void k_wpacke(const float* __restrict__ wih,
                                                _Float16* __restrict__ wpe){
  int tid = blockIdx.x * 256 + threadIdx.x;
  if (tid >= 12 * 64) return;
  int tile = tid >> 6, l = tid & 63;
  #pragma unroll
  for (int i = 0; i < 8; ++i){
    int row = tile * 16 + (l & 15);         // w_ih row = output index j
    int col = (l >> 4) * 8 + i;             // w_ih col = k (0..31)
    wpe[(size_t)tid * 8 + i] = (_Float16)wih[row * ES + col];
  }
}

// ---------------- K6: recurrence. Block = 2 waves, u-dim split across them. -
// Wave `half` owns hidden units [32*half, 32*half+32). Input-side matmul is
// fused via MFMA on an emb f16 A-fragment (1 contiguous 16B load/lane/step)
// instead of the old gxtab gather (~290 scattered lines/step). 18 MFMAs per
// wave-step: r,z = e+2h chained with biases folded in C-init; n keeps
// separate e- and h-accumulators (b_hh[n] is scaled by r).
__global__ __launch_bounds__(128, 2) void k_gru(
    const int* __restrict__ x, const _Float16* __restrict__ ef,
    const _Float16* __restrict__ wpk, const _Float16* __restrict__ wpe,
    const float* __restrict__ bih, const float* __restrict__ bhh,
    const int* __restrict__ perm, const int* __restrict__ len,
    float* __restrict__ out)
{
  __shared__ __align__(16) _Float16 hb[2][16 * LDH];
  int half = threadIdx.x >> 6;           // which u-half this wave owns
  int grp  = blockIdx.x;                 // 16 sorted seqs per block
  int lane = threadIdx.x & 63;
  int q = lane >> 4, c = lane & 15;

  // resident B fragments: h-side 3 gates x 2 lt x 2 kf (48 VGPR),
  // e-side 3 gates x 2 lt (24 VGPR)
  v8h bfh[3][2][2], bfe[3][2];
  #pragma unroll
  for (int g = 0; g < 3; ++g)
    #pragma unroll
    for (int lt = 0; lt < 2; ++lt){
      int tile = g*4 + half*2 + lt;
      #pragma unroll
      for (int kf = 0; kf < 2; ++kf)
        bfh[g][lt][kf] = *(const v8h*)(wpk + ((size_t)(tile*2 + kf)*64 + lane)*8);
      bfe[g][lt] = *(const v8h*)(wpe + ((size_t)tile*64 + lane)*8);
    }

  int sq[4], ln[4];
  #pragma unroll
  for (int r = 0; r < 4; ++r){
    int s = perm[grp * 16 + q*4 + r];
    sq[r] = s;
    ln[r] = len[s];
  }
  // per-lane biases for owned units u = half*32 + lt*16 + c
  float br[2], bz[2], ben[2], bhn[2];
  #pragma unroll
  for (int lt = 0; lt < 2; ++lt){
    int u = half*32 + lt*16 + c;
    br[lt]  = bih[u]        + bhh[u];
    bz[lt]  = bih[HS + u]   + bhh[HS + u];
    ben[lt] = bih[2*HS + u];
    bhn[lt] = bhh[2*HS + u];
  }

  float h[2][4];   // h[lt][r]: unit half*32+lt*16+c of seq m = q*4+r
  #pragma unroll
  for (int lt = 0; lt < 2; ++lt)
    #pragma unroll
    for (int r = 0; r < 4; ++r) h[lt][r] = 0.f;

  for (int i = threadIdx.x; i < 16*LDH; i += 128) hb[0][i] = (_Float16)0.f;
  __syncthreads();

  int tmax = max(max(ln[0], ln[1]), max(ln[2], ln[3]));
  tmax = max(tmax, __shfl_xor(tmax, 16, 64));
  tmax = max(tmax, __shfl_xor(tmax, 32, 64));

  // A-row m = c sequence id (for emb/token prefetch; 16 distinct addrs/wave)
  int sq_m = perm[grp * 16 + c];

  // pipeline: aec = emb A-frag for step t; tk1 = token for t+1
  v8h aec, aen;
  int tk1, tk2;
  {
    int tk0 = x[(size_t)sq_m * LSEQ + 0];
    aec = *(const v8h*)(ef + (size_t)tk0 * ES + q*8);
    tk1 = x[(size_t)sq_m * LSEQ + 1];
  }

  #define GRU_STEP(AEC, AEN, TKN_, TKNN_, RB, WB)                              \
  {                                                                            \
    AEN = *(const v8h*)(ef + (size_t)TKN_ * ES + q*8);   /* emb frag t+1 */    \
    int t2 = min(t + 2, LSEQ - 1);                                             \
    TKNN_ = x[(size_t)sq_m * LSEQ + t2];                 /* token t+2 */       \
    v8h a0 = *(const v8h*)(&hb[RB][c*LDH + q*8]);                              \
    v8h a1 = *(const v8h*)(&hb[RB][c*LDH + 32 + q*8]);                         \
    v4f Dr[2], Dz[2], Dhn[2], Den[2];                                          \
    _Pragma("unroll")                                                          \
    for (int lt = 0; lt < 2; ++lt){                                            \
      v4f zr; zr[0]=br[lt]; zr[1]=br[lt]; zr[2]=br[lt]; zr[3]=br[lt];          \
      zr = __builtin_amdgcn_mfma_f32_16x16x32_f16(a0,  bfh[0][lt][0], zr,0,0,0);\
      zr = __builtin_amdgcn_mfma_f32_16x16x32_f16(a1,  bfh[0][lt][1], zr,0,0,0);\
      Dr[lt] = __builtin_amdgcn_mfma_f32_16x16x32_f16(AEC, bfe[0][lt], zr,0,0,0);\
      v4f zz; zz[0]=bz[lt]; zz[1]=bz[lt]; zz[2]=bz[lt]; zz[3]=bz[lt];          \
      zz = __builtin_amdgcn_mfma_f32_16x16x32_f16(a0,  bfh[1][lt][0], zz,0,0,0);\
      zz = __builtin_amdgcn_mfma_f32_16x16x32_f16(a1,  bfh[1][lt][1], zz,0,0,0);\
      Dz[lt] = __builtin_amdgcn_mfma_f32_16x16x32_f16(AEC, bfe[1][lt], zz,0,0,0);\
      v4f zh; zh[0]=bhn[lt]; zh[1]=bhn[lt]; zh[2]=bhn[lt]; zh[3]=bhn[lt];      \
      zh = __builtin_amdgcn_mfma_f32_16x16x32_f16(a0,  bfh[2][lt][0], zh,0,0,0);\
      Dhn[lt] = __builtin_amdgcn_mfma_f32_16x16x32_f16(a1, bfh[2][lt][1], zh,0,0,0);\
      v4f ze; ze[0]=ben[lt]; ze[1]=ben[lt]; ze[2]=ben[lt]; ze[3]=ben[lt];      \
      Den[lt] = __builtin_amdgcn_mfma_f32_16x16x32_f16(AEC, bfe[2][lt], ze,0,0,0);\
    }                                                                          \
    _Pragma("unroll")                                                          \
    for (int lt = 0; lt < 2; ++lt){                                            \
      _Pragma("unroll")                                                        \
      for (int r = 0; r < 4; ++r){                                             \
        float rg   = sig_fast(Dr[lt][r]);                                      \
        float zg   = sig_fast(Dz[lt][r]);                                      \
        float ng   = tanh_fast(Den[lt][r] + rg * Dhn[lt][r]);                  \
        float hnew = ng + zg * (h[lt][r] - ng);                                \
        h[lt][r]   = (t < ln[r]) ? hnew : h[lt][r];                            \
      }                                                                        \
    }                                                                          \
    _Pragma("unroll")                                                          \
    for (int lt = 0; lt < 2; ++lt)                                             \
      _Pragma("unroll")                                                        \
      for (int r = 0; r < 4; ++r)                                              \
        hb[WB][(q*4 + r)*LDH + half*32 + lt*16 + c] = (_Float16)h[lt][r];      \
    __syncthreads();                                                           \
  }

  int t = 0;
  for (; t + 1 < tmax; ){
    GRU_STEP(aec, aen, tk1, tk2, 0, 1); ++t;
    GRU_STEP(aen, aec, tk2, tk1, 1, 0); ++t;
  }
  if (t < tmax){
    GRU_STEP(aec, aen, tk1, tk2, 0, 1); ++t;
  }
  #undef GRU_STEP

  #pragma unroll
  for (int lt = 0; lt < 2; ++lt)
    #pragma unroll
    for (int r = 0; r < 4; ++r)
      out[(size_t)sq[r] * HS + half*32 + lt*16 + c] = h[lt][r];
}

extern "C" void kernel_launch(void* const* d_in, const int* in_sizes, int n_in,
                              void* d_out, int out_size, void* d_ws, size_t ws_size,
                              hipStream_t stream){
  const int*   x   = (const int*)  d_in[0];
  const float* emb = (const float*)d_in[1];
  const float* wih = (const float*)d_in[2];
  const float* whh = (const float*)d_in[3];
  const float* bih = (const float*)d_in[4];
  const float* bhh = (const float*)d_in[5];
  float* out = (float*)d_out;

  char* ws = (char*)d_ws;
  size_t off = 0;
  _Float16* ef  = (_Float16*)(ws + off);  off += (size_t)VOCAB * ES * sizeof(_Float16);
  _Float16* wpk = (_Float16*)(ws + off);  off += (size_t)24 * 64 * 8 * sizeof(_Float16);
  _Float16* wpe = (_Float16*)(ws + off);  off += (size_t)12 * 64 * 8 * sizeof(_Float16);
  off = (off + 255) & ~(size_t)255;
  int* len  = (int*)(ws + off);           off += (size_t)N_SEQ * sizeof(int);
  int* perm = (int*)(ws + off);           off += (size_t)N_SEQ * sizeof(int);
  int* hist = (int*)(ws + off);           off += 513 * sizeof(int);
  off = (off + 255) & ~(size_t)255;
  int* offs = (int*)(ws + off);           off += 513 * sizeof(int);

  hipMemsetAsync(hist, 0, 513 * sizeof(int), stream);
  k_len    <<<N_SEQ / 4,   256, 0, stream>>>(x, len, hist);
  k_scan   <<<1,          1024, 0, stream>>>(hist, offs);
  k_scatter<<<N_SEQ / 256, 256, 0, stream>>>(len, offs, perm);
  k_emb    <<<(VOCAB*ES + 255)/256, 256, 0, stream>>>(emb, ef);
  k_wpack  <<<6,           256, 0, stream>>>(whh, wpk);
  k_wpacke <<<3,           256, 0, stream>>>(wih, wpe);
  k_gru    <<<N_SEQ / 16,  128, 0, stream>>>(x, ef, wpk, wpe, bih, bhh, perm, len, out);
}

// Round 6
// 408.182 us; speedup vs baseline: 3.4488x; 1.3999x over previous
//
#include <hip/hip_runtime.h>

#define N_SEQ 16384
#define LSEQ  512
#define VOCAB 32000
#define ES    32
#define HS    64
#define LDH   72    // padded f16 stride per m-row in LDS

typedef _Float16 v8h __attribute__((ext_vector_type(8)));
typedef float    v4f __attribute__((ext_vector_type(4)));

__device__ __forceinline__ float sig_fast(float x){
  float t = __builtin_amdgcn_exp2f(x * -1.4426950408889634f);
  return __builtin_amdgcn_rcpf(1.f + t);
}
__device__ __forceinline__ float tanh_fast(float x){
  x = fminf(fmaxf(x, -15.f), 15.f);
  float t = __builtin_amdgcn_exp2f(x * -2.8853900817779268f); // e^{-2x}
  return (1.f - t) * __builtin_amdgcn_rcpf(1.f + t);
}

// ---------------- K1: lengths + histogram (one wave per row) ----------------
__global__ __launch_bounds__(256) void k_len(const int* __restrict__ x,
                                             int* __restrict__ len,
                                             int* __restrict__ hist){
  int wid  = (blockIdx.x * 256 + threadIdx.x) >> 6;
  int lane = threadIdx.x & 63;
  const int* xr = x + (size_t)wid * LSEQ;
  int cnt = 0;
  #pragma unroll
  for (int j = 0; j < 8; ++j) cnt += (xr[lane + 64*j] != 0) ? 1 : 0;
  #pragma unroll
  for (int o = 32; o; o >>= 1) cnt += __shfl_down(cnt, o, 64);
  if (lane == 0){ len[wid] = cnt; atomicAdd(&hist[cnt], 1); }
}

// ---------------- K2: exclusive scan of hist[0..512] -> offs ----------------
__global__ __launch_bounds__(1024) void k_scan(const int* __restrict__ hist,
                                               int* __restrict__ offs){
  __shared__ int buf[1024];
  int i = threadIdx.x;
  buf[i] = (i < 513) ? hist[i] : 0;
  __syncthreads();
  for (int d = 1; d < 1024; d <<= 1){
    int v = (i >= d) ? buf[i - d] : 0;
    __syncthreads();
    buf[i] += v;
    __syncthreads();
  }
  if (i < 513) offs[i] = (i == 0) ? 0 : buf[i - 1];
}

// ---------------- K3: scatter seq ids sorted (ascending) by length ----------
__global__ __launch_bounds__(256) void k_scatter(const int* __restrict__ len,
                                                 int* __restrict__ offs,
                                                 int* __restrict__ perm){
  int i = blockIdx.x * 256 + threadIdx.x;
  int l = len[i];
  int pos = atomicAdd(&offs[l], 1);
  perm[pos] = i;
}

// ---------------- K4: embedding f32 -> f16 (row-contiguous, 64B/row) --------
__global__ __launch_bounds__(256) void k_emb(const float* __restrict__ emb,
                                             _Float16* __restrict__ ef){
  int i = blockIdx.x * 256 + threadIdx.x;
  if (i < VOCAB * ES) ef[i] = (_Float16)emb[i];
}

// ---------------- K5a: pack w_hh into f16 B-fragment layout (K=64: 2 frags) -
__global__ __launch_bounds__(256) void k_wpack(const float* __restrict__ whh,
                                               _Float16* __restrict__ wpk){
  int tid = blockIdx.x * 256 + threadIdx.x;
  if (tid >= 24 * 64) return;
  int f = tid >> 6, l = tid & 63;
  int jt = f >> 1, kf = f & 1;
  #pragma unroll
  for (int i = 0; i < 8; ++i){
    int row = jt * 16 + (l & 15);           // w_hh row = output index j
    int col = kf * 32 + (l >> 4) * 8 + i;   // w_hh col = k
    wpk[(size_t)tid * 8 + i] = (_Float16)whh[row * HS + col];
  }
}

// ---------------- K5b: pack w_ih into f16 B-fragment layout (K=32: 1 frag) --
__global__ __launch_bounds__(256) void k_wpacke(const float* __restrict__ wih,
                                                _Float16* __restrict__ wpe){
  int tid = blockIdx.x * 256 + threadIdx.x;
  if (tid >= 12 * 64) return;
  int tile = tid >> 6, l = tid & 63;
  #pragma unroll
  for (int i = 0; i < 8; ++i){
    int row = tile * 16 + (l & 15);         // w_ih row = output index j
    int col = (l >> 4) * 8 + i;             // w_ih col = k (0..31)
    wpe[(size_t)tid * 8 + i] = (_Float16)wih[row * ES + col];
  }
}

// ---------------- K6: recurrence. Block = 4 waves; wave qt owns u-quarter ---
// [16*qt, 16*qt+16): one 16-wide j-tile per gate -> 9 MFMAs, 24 transcendental
// instrs per wave-step. Input-side matmul fused via emb f16 A-fragment (one
// contiguous 16B load/lane/step). Ping-pong LDS h + one __syncthreads/step.
// Blocks dispatched longest-first so 512-step blocks start at t=0; 4 blocks/CU
// give 4 independent wave-chains per SIMD to hide each chain's latency.
__global__ __launch_bounds__(256, 4) void k_gru(
    const int* __restrict__ x, const _Float16* __restrict__ ef,
    const _Float16* __restrict__ wpk, const _Float16* __restrict__ wpe,
    const float* __restrict__ bih, const float* __restrict__ bhh,
    const int* __restrict__ perm, const int* __restrict__ len,
    float* __restrict__ out)
{
  __shared__ __align__(16) _Float16 hb[2][16 * LDH];
  int qt   = threadIdx.x >> 6;                        // u-quarter of this wave
  int grp  = (int)gridDim.x - 1 - (int)blockIdx.x;    // longest-first
  int lane = threadIdx.x & 63;
  int q = lane >> 4, c = lane & 15;
  int uu = qt*16 + c;                                 // owned unit (per gate)

  // resident B fragments: h-side 3 gates x 2 kf (24 VGPR), e-side 3 (12 VGPR)
  v8h bfh[3][2], bfe[3];
  #pragma unroll
  for (int g = 0; g < 3; ++g){
    int tile = g*4 + qt;
    #pragma unroll
    for (int kf = 0; kf < 2; ++kf)
      bfh[g][kf] = *(const v8h*)(wpk + ((size_t)(tile*2 + kf)*64 + lane)*8);
    bfe[g] = *(const v8h*)(wpe + ((size_t)tile*64 + lane)*8);
  }

  int sq[4], ln[4];
  #pragma unroll
  for (int r = 0; r < 4; ++r){
    int s = perm[grp * 16 + q*4 + r];
    sq[r] = s;
    ln[r] = len[s];
  }
  // per-lane biases for owned unit uu
  float br  = bih[uu]        + bhh[uu];
  float bz  = bih[HS + uu]   + bhh[HS + uu];
  float ben = bih[2*HS + uu];
  float bhn = bhh[2*HS + uu];

  float h[4];   // h[r]: unit uu of seq m = q*4+r
  #pragma unroll
  for (int r = 0; r < 4; ++r) h[r] = 0.f;

  for (int i = threadIdx.x; i < 16*LDH; i += 256) hb[0][i] = (_Float16)0.f;
  __syncthreads();

  int tmax = max(max(ln[0], ln[1]), max(ln[2], ln[3]));
  tmax = max(tmax, __shfl_xor(tmax, 16, 64));
  tmax = max(tmax, __shfl_xor(tmax, 32, 64));

  // A-row m = c sequence id (for emb/token prefetch; 16 distinct addrs/wave)
  int sq_m = perm[grp * 16 + c];

  // pipeline: aec = emb A-frag for step t; tk1 = token for t+1
  v8h aec, aen;
  int tk1, tk2;
  {
    int tk0 = x[(size_t)sq_m * LSEQ + 0];
    aec = *(const v8h*)(ef + (size_t)tk0 * ES + q*8);
    tk1 = x[(size_t)sq_m * LSEQ + 1];
  }

  #define GRU_STEP(AEC, AEN, TKN_, TKNN_, RB, WB)                              \
  {                                                                            \
    AEN = *(const v8h*)(ef + (size_t)TKN_ * ES + q*8);   /* emb frag t+1 */    \
    int t2 = min(t + 2, LSEQ - 1);                                             \
    TKNN_ = x[(size_t)sq_m * LSEQ + t2];                 /* token t+2 */       \
    v8h a0 = *(const v8h*)(&hb[RB][c*LDH + q*8]);                              \
    v8h a1 = *(const v8h*)(&hb[RB][c*LDH + 32 + q*8]);                         \
    v4f zr; zr[0]=br; zr[1]=br; zr[2]=br; zr[3]=br;                            \
    zr = __builtin_amdgcn_mfma_f32_16x16x32_f16(a0,  bfh[0][0], zr,0,0,0);     \
    zr = __builtin_amdgcn_mfma_f32_16x16x32_f16(a1,  bfh[0][1], zr,0,0,0);     \
    v4f Dr = __builtin_amdgcn_mfma_f32_16x16x32_f16(AEC, bfe[0], zr,0,0,0);    \
    v4f zz; zz[0]=bz; zz[1]=bz; zz[2]=bz; zz[3]=bz;                            \
    zz = __builtin_amdgcn_mfma_f32_16x16x32_f16(a0,  bfh[1][0], zz,0,0,0);     \
    zz = __builtin_amdgcn_mfma_f32_16x16x32_f16(a1,  bfh[1][1], zz,0,0,0);     \
    v4f Dz = __builtin_amdgcn_mfma_f32_16x16x32_f16(AEC, bfe[1], zz,0,0,0);    \
    v4f zh; zh[0]=bhn; zh[1]=bhn; zh[2]=bhn; zh[3]=bhn;                        \
    zh = __builtin_amdgcn_mfma_f32_16x16x32_f16(a0,  bfh[2][0], zh,0,0,0);     \
    v4f Dhn = __builtin_amdgcn_mfma_f32_16x16x32_f16(a1, bfh[2][1], zh,0,0,0); \
    v4f ze; ze[0]=ben; ze[1]=ben; ze[2]=ben; ze[3]=ben;                        \
    v4f Den = __builtin_amdgcn_mfma_f32_16x16x32_f16(AEC, bfe[2], ze,0,0,0);   \
    _Pragma("unroll")                                                          \
    for (int r = 0; r < 4; ++r){                                               \
      float rg   = sig_fast(Dr[r]);                                            \
      float zg   = sig_fast(Dz[r]);                                            \
      float ng   = tanh_fast(Den[r] + rg * Dhn[r]);                            \
      float hnew = ng + zg * (h[r] - ng);                                      \
      h[r]       = (t < ln[r]) ? hnew : h[r];                                  \
    }                                                                          \
    _Pragma("unroll")                                                          \
    for (int r = 0; r < 4; ++r)                                                \
      hb[WB][(q*4 + r)*LDH + uu] = (_Float16)h[r];                             \
    __syncthreads();                                                           \
  }

  int t = 0;
  for (; t + 1 < tmax; ){
    GRU_STEP(aec, aen, tk1, tk2, 0, 1); ++t;
    GRU_STEP(aen, aec, tk2, tk1, 1, 0); ++t;
  }
  if (t < tmax){
    GRU_STEP(aec, aen, tk1, tk2, 0, 1); ++t;
  }
  #undef GRU_STEP

  #pragma unroll
  for (int r = 0; r < 4; ++r)
    out[(size_t)sq[r] * HS + uu] = h[r];
}

extern "C" void kernel_launch(void* const* d_in, const int* in_sizes, int n_in,
                              void* d_out, int out_size, void* d_ws, size_t ws_size,
                              hipStream_t stream){
  const int*   x   = (const int*)  d_in[0];
  const float* emb = (const float*)d_in[1];
  const float* wih = (const float*)d_in[2];
  const float* whh = (const float*)d_in[3];
  const float* bih = (const float*)d_in[4];
  const float* bhh = (const float*)d_in[5];
  float* out = (float*)d_out;

  char* ws = (char*)d_ws;
  size_t off = 0;
  _Float16* ef  = (_Float16*)(ws + off);  off += (size_t)VOCAB * ES * sizeof(_Float16);
  _Float16* wpk = (_Float16*)(ws + off);  off += (size_t)24 * 64 * 8 * sizeof(_Float16);
  _Float16* wpe = (_Float16*)(ws + off);  off += (size_t)12 * 64 * 8 * sizeof(_Float16);
  off = (off + 255) & ~(size_t)255;
  int* len  = (int*)(ws + off);           off += (size_t)N_SEQ * sizeof(int);
  int* perm = (int*)(ws + off);           off += (size_t)N_SEQ * sizeof(int);
  int* hist = (int*)(ws + off);           off += 513 * sizeof(int);
  off = (off + 255) & ~(size_t)255;
  int* offs = (int*)(ws + off);           off += 513 * sizeof(int);

  hipMemsetAsync(hist, 0, 513 * sizeof(int), stream);
  k_len    <<<N_SEQ / 4,   256, 0, stream>>>(x, len, hist);
  k_scan   <<<1,          1024, 0, stream>>>(hist, offs);
  k_scatter<<<N_SEQ / 256, 256, 0, stream>>>(len, offs, perm);
  k_emb    <<<(VOCAB*ES + 255)/256, 256, 0, stream>>>(emb, ef);
  k_wpack  <<<6,           256, 0, stream>>>(whh, wpk);
  k_wpacke <<<3,           256, 0, stream>>>(wih, wpe);
  k_gru    <<<N_SEQ / 16,  256, 0, stream>>>(x, ef, wpk, wpe, bih, bhh, perm, len, out);
}

// Round 7
// 355.354 us; speedup vs baseline: 3.9615x; 1.1487x over previous
//
#include <hip/hip_runtime.h>

#define N_SEQ 16384
#define LSEQ  512
#define VOCAB 32000
#define ES    32
#define HS    64
#define LDH   72    // padded f16 stride per m-row in LDS

typedef _Float16 v8h __attribute__((ext_vector_type(8)));
typedef float    v4f __attribute__((ext_vector_type(4)));

__device__ __forceinline__ float sig_fast(float x){
  float t = __builtin_amdgcn_exp2f(x * -1.4426950408889634f);
  return __builtin_amdgcn_rcpf(1.f + t);
}
__device__ __forceinline__ float tanh_fast(float x){
  // lower guard only: x<=-44 would give inf*0=NaN; args are O(5) but guard is 1 instr
  x = fmaxf(x, -30.f);
  float t = __builtin_amdgcn_exp2f(x * -2.8853900817779268f); // e^{-2x}
  return (1.f - t) * __builtin_amdgcn_rcpf(1.f + t);
}

// ---------------- K1 (fused prep): lengths+hist | emb->f16 | weight packs ---
#define NLB (N_SEQ / 4)            // 4096 blocks: lengths
#define NEB (VOCAB * ES / 256)     // 4000 blocks: emb convert
__global__ __launch_bounds__(256) void k_prep(const int* __restrict__ x,
                                              const float* __restrict__ emb,
                                              const float* __restrict__ whh,
                                              const float* __restrict__ wih,
                                              int* __restrict__ len,
                                              int* __restrict__ hist,
                                              _Float16* __restrict__ ef,
                                              _Float16* __restrict__ wpk,
                                              _Float16* __restrict__ wpe){
  int b = blockIdx.x;
  if (b < NLB){                               // ---- lengths + histogram
    int wid  = (b * 256 + threadIdx.x) >> 6;
    int lane = threadIdx.x & 63;
    const int* xr = x + (size_t)wid * LSEQ;
    int cnt = 0;
    #pragma unroll
    for (int j = 0; j < 8; ++j) cnt += (xr[lane + 64*j] != 0) ? 1 : 0;
    #pragma unroll
    for (int o = 32; o; o >>= 1) cnt += __shfl_down(cnt, o, 64);
    if (lane == 0){ len[wid] = cnt; atomicAdd(&hist[cnt], 1); }
  } else if (b < NLB + NEB){                  // ---- embedding f32 -> f16
    int i = (b - NLB) * 256 + threadIdx.x;
    ef[i] = (_Float16)emb[i];
  } else if (b < NLB + NEB + 6){              // ---- pack w_hh (K=64: 2 frags)
    int tid = (b - NLB - NEB) * 256 + threadIdx.x;
    int f = tid >> 6, l = tid & 63;
    int jt = f >> 1, kf = f & 1;
    #pragma unroll
    for (int i = 0; i < 8; ++i){
      int row = jt * 16 + (l & 15);
      int col = kf * 32 + (l >> 4) * 8 + i;
      wpk[(size_t)tid * 8 + i] = (_Float16)whh[row * HS + col];
    }
  } else {                                    // ---- pack w_ih (K=32: 1 frag)
    int tid = (b - NLB - NEB - 6) * 256 + threadIdx.x;
    int tile = tid >> 6, l = tid & 63;
    #pragma unroll
    for (int i = 0; i < 8; ++i){
      int row = tile * 16 + (l & 15);
      int col = (l >> 4) * 8 + i;
      wpe[(size_t)tid * 8 + i] = (_Float16)wih[row * ES + col];
    }
  }
}

// ---------------- K2: exclusive scan of hist[0..512] -> offs ----------------
__global__ __launch_bounds__(1024) void k_scan(const int* __restrict__ hist,
                                               int* __restrict__ offs){
  __shared__ int buf[1024];
  int i = threadIdx.x;
  buf[i] = (i < 513) ? hist[i] : 0;
  __syncthreads();
  for (int d = 1; d < 1024; d <<= 1){
    int v = (i >= d) ? buf[i - d] : 0;
    __syncthreads();
    buf[i] += v;
    __syncthreads();
  }
  if (i < 513) offs[i] = (i == 0) ? 0 : buf[i - 1];
}

// ---------------- K3: scatter seq ids sorted (ascending) by length ----------
__global__ __launch_bounds__(256) void k_scatter(const int* __restrict__ len,
                                                 int* __restrict__ offs,
                                                 int* __restrict__ perm){
  int i = blockIdx.x * 256 + threadIdx.x;
  int l = len[i];
  int pos = atomicAdd(&offs[l], 1);
  perm[pos] = i;
}

// ---------------- K4: recurrence. Block = 4 waves; wave qt owns u-quarter ---
// [16*qt,16*qt+16). Serpentine blockIdx->rank mapping equalizes per-CU work
// under round-robin dispatch (i=k mod 256 -> same CU): CU k's four blocks sum
// to ~1024 block-steps instead of 1280-2k. e-side MFMAs (Den + e-partials of
// r,z) for step t+1 are issued just before the barrier so the barrier drain
// hides their latency; post-barrier chain is 2 MFMAs. Biases live in hoisted
// accumulator-init quads.
__global__ __launch_bounds__(256, 4) void k_gru(
    const int* __restrict__ x, const _Float16* __restrict__ ef,
    const _Float16* __restrict__ wpk, const _Float16* __restrict__ wpe,
    const float* __restrict__ bih, const float* __restrict__ bhh,
    const int* __restrict__ perm, const int* __restrict__ len,
    float* __restrict__ out)
{
  __shared__ __align__(16) _Float16 hb[2][16 * LDH];
  int qt   = threadIdx.x >> 6;
  // serpentine rank: quarters 0,2 ascend; 1,3 descend -> per-CU totals equal
  int w = blockIdx.x >> 8, cq = blockIdx.x & 255;
  int rank = w * 256 + ((w & 1) ? (255 - cq) : cq);   // 0 = longest
  int grp  = 1023 - rank;                             // ascending-sorted index
  int lane = threadIdx.x & 63;
  int q = lane >> 4, c = lane & 15;
  int uu = qt*16 + c;

  // resident B fragments: h-side 3 gates x 2 kf (24 VGPR), e-side 3 (12 VGPR)
  v8h bfh[3][2], bfe[3];
  #pragma unroll
  for (int g = 0; g < 3; ++g){
    int tile = g*4 + qt;
    #pragma unroll
    for (int kf = 0; kf < 2; ++kf)
      bfh[g][kf] = *(const v8h*)(wpk + ((size_t)(tile*2 + kf)*64 + lane)*8);
    bfe[g] = *(const v8h*)(wpe + ((size_t)tile*64 + lane)*8);
  }

  int sq[4], ln[4];
  #pragma unroll
  for (int r = 0; r < 4; ++r){
    int s = perm[grp * 16 + q*4 + r];
    sq[r] = s;
    ln[r] = len[s];
  }
  // bias accumulator-init quads (hoisted; broadcast over the 4 C-rows)
  float br  = bih[uu]        + bhh[uu];
  float bz  = bih[HS + uu]   + bhh[HS + uu];
  float ben = bih[2*HS + uu];
  float bhn = bhh[2*HS + uu];
  v4f brq  = {br, br, br, br};
  v4f bzq  = {bz, bz, bz, bz};
  v4f benq = {ben, ben, ben, ben};
  v4f bhnq = {bhn, bhn, bhn, bhn};

  float h[4];
  #pragma unroll
  for (int r = 0; r < 4; ++r) h[r] = 0.f;

  for (int i = threadIdx.x; i < 16*LDH; i += 256) hb[0][i] = (_Float16)0.f;
  __syncthreads();

  int tmax = max(max(ln[0], ln[1]), max(ln[2], ln[3]));
  tmax = max(tmax, __shfl_xor(tmax, 16, 64));
  tmax = max(tmax, __shfl_xor(tmax, 32, 64));

  const int* xr = x + (size_t)perm[grp * 16 + c] * LSEQ;  // A-row m=c tokens

  // pipeline state: aec/aen = emb frag (t / t+1); pr*/de* = e-side accs
  v8h aec, aen;
  int tk1, tk2;
  v4f pra, prb, pza, pzb, dea, deb;   // e-partials: r, z, n (ping/pong)
  {
    int tk0 = xr[0];
    aec = *(const v8h*)(ef + (size_t)tk0 * ES + q*8);
    tk1 = xr[1];
    pra = __builtin_amdgcn_mfma_f32_16x16x32_f16(aec, bfe[0], brq,  0,0,0);
    pza = __builtin_amdgcn_mfma_f32_16x16x32_f16(aec, bfe[1], bzq,  0,0,0);
    dea = __builtin_amdgcn_mfma_f32_16x16x32_f16(aec, bfe[2], benq, 0,0,0);
  }

  #define GRU_STEP(AEN, PRR, PRZ, DEN, PRRn, PRZn, DENn, TKN_, TKNN_, RB, WB) \
  {                                                                            \
    AEN = *(const v8h*)(ef + (size_t)TKN_ * ES + q*8);   /* emb frag t+1 */    \
    int t2 = min(t + 2, LSEQ - 1);                                             \
    TKNN_ = xr[t2];                                      /* token t+2 */       \
    v8h a0 = *(const v8h*)(&hb[RB][c*LDH + q*8]);                              \
    v8h a1 = *(const v8h*)(&hb[RB][c*LDH + 32 + q*8]);                         \
    v4f zr  = __builtin_amdgcn_mfma_f32_16x16x32_f16(a1, bfh[0][1], PRR, 0,0,0);\
    v4f Dr  = __builtin_amdgcn_mfma_f32_16x16x32_f16(a0, bfh[0][0], zr,  0,0,0);\
    v4f zz  = __builtin_amdgcn_mfma_f32_16x16x32_f16(a1, bfh[1][1], PRZ, 0,0,0);\
    v4f Dz  = __builtin_amdgcn_mfma_f32_16x16x32_f16(a0, bfh[1][0], zz,  0,0,0);\
    v4f zh  = __builtin_amdgcn_mfma_f32_16x16x32_f16(a1, bfh[2][1], bhnq,0,0,0);\
    v4f Dhn = __builtin_amdgcn_mfma_f32_16x16x32_f16(a0, bfh[2][0], zh,  0,0,0);\
    _Pragma("unroll")                                                          \
    for (int r = 0; r < 4; ++r){                                               \
      float rg   = sig_fast(Dr[r]);                                            \
      float zg   = sig_fast(Dz[r]);                                            \
      float ng   = tanh_fast(DEN[r] + rg * Dhn[r]);                            \
      float hnew = ng + zg * (h[r] - ng);                                      \
      h[r]       = (t < ln[r]) ? hnew : h[r];                                  \
    }                                                                          \
    /* e-side accs for t+1: issued pre-barrier, latency hidden by the drain */ \
    PRRn = __builtin_amdgcn_mfma_f32_16x16x32_f16(AEN, bfe[0], brq,  0,0,0);   \
    PRZn = __builtin_amdgcn_mfma_f32_16x16x32_f16(AEN, bfe[1], bzq,  0,0,0);   \
    DENn = __builtin_amdgcn_mfma_f32_16x16x32_f16(AEN, bfe[2], benq, 0,0,0);   \
    _Pragma("unroll")                                                          \
    for (int r = 0; r < 4; ++r)                                                \
      hb[WB][(q*4 + r)*LDH + uu] = (_Float16)h[r];                             \
    __syncthreads();                                                           \
  }

  int t = 0;
  for (; t + 1 < tmax; ){
    GRU_STEP(aen, pra, pza, dea, prb, pzb, deb, tk1, tk2, 0, 1); ++t;
    GRU_STEP(aec, prb, pzb, deb, pra, pza, dea, tk2, tk1, 1, 0); ++t;
  }
  if (t < tmax){
    GRU_STEP(aen, pra, pza, dea, prb, pzb, deb, tk1, tk2, 0, 1); ++t;
  }
  #undef GRU_STEP

  #pragma unroll
  for (int r = 0; r < 4; ++r)
    out[(size_t)sq[r] * HS + uu] = h[r];
}

extern "C" void kernel_launch(void* const* d_in, const int* in_sizes, int n_in,
                              void* d_out, int out_size, void* d_ws, size_t ws_size,
                              hipStream_t stream){
  const int*   x   = (const int*)  d_in[0];
  const float* emb = (const float*)d_in[1];
  const float* wih = (const float*)d_in[2];
  const float* whh = (const float*)d_in[3];
  const float* bih = (const float*)d_in[4];
  const float* bhh = (const float*)d_in[5];
  float* out = (float*)d_out;

  char* ws = (char*)d_ws;
  size_t off = 0;
  _Float16* ef  = (_Float16*)(ws + off);  off += (size_t)VOCAB * ES * sizeof(_Float16);
  _Float16* wpk = (_Float16*)(ws + off);  off += (size_t)24 * 64 * 8 * sizeof(_Float16);
  _Float16* wpe = (_Float16*)(ws + off);  off += (size_t)12 * 64 * 8 * sizeof(_Float16);
  off = (off + 255) & ~(size_t)255;
  int* len  = (int*)(ws + off);           off += (size_t)N_SEQ * sizeof(int);
  int* perm = (int*)(ws + off);           off += (size_t)N_SEQ * sizeof(int);
  int* hist = (int*)(ws + off);           off += 513 * sizeof(int);
  off = (off + 255) & ~(size_t)255;
  int* offs = (int*)(ws + off);           off += 513 * sizeof(int);

  hipMemsetAsync(hist, 0, 513 * sizeof(int), stream);
  k_prep   <<<NLB + NEB + 9, 256, 0, stream>>>(x, emb, whh, wih, len, hist, ef, wpk, wpe);
  k_scan   <<<1,            1024, 0, stream>>>(hist, offs);
  k_scatter<<<N_SEQ / 256,   256, 0, stream>>>(len, offs, perm);
  k_gru    <<<N_SEQ / 16,    256, 0, stream>>>(x, ef, wpk, wpe, bih, bhh, perm, len, out);
}

// Round 8
// 324.762 us; speedup vs baseline: 4.3346x; 1.0942x over previous
//
#include <hip/hip_runtime.h>

#define N_SEQ 16384
#define LSEQ  512
#define VOCAB 32000
#define ES    32
#define HS    64
#define LDH   72    // padded f16 stride per m-row in LDS

#define SC_RZ (-1.4426950408889634f)   // -log2(e): folded into r,z weights
#define SC_N  (-2.8853900817779268f)   // -2*log2(e): folded into n weights

typedef _Float16 v8h __attribute__((ext_vector_type(8)));
typedef float    v4f __attribute__((ext_vector_type(4)));

// ---------------- K1 (fused prep): lengths+hist | emb->f16 | weight packs ---
#define NLB (N_SEQ / 4)            // 4096 blocks: lengths
#define NEB (VOCAB * ES / 256)     // 4000 blocks: emb convert
__global__ __launch_bounds__(256) void k_prep(const int* __restrict__ x,
                                              const float* __restrict__ emb,
                                              const float* __restrict__ whh,
                                              const float* __restrict__ wih,
                                              int* __restrict__ len,
                                              int* __restrict__ hist,
                                              _Float16* __restrict__ ef,
                                              _Float16* __restrict__ wpk,
                                              _Float16* __restrict__ wpe){
  int b = blockIdx.x;
  if (b < NLB){                               // ---- lengths + histogram
    int wid  = (b * 256 + threadIdx.x) >> 6;
    int lane = threadIdx.x & 63;
    const int* xr = x + (size_t)wid * LSEQ;
    int cnt = 0;
    #pragma unroll
    for (int j = 0; j < 8; ++j) cnt += (xr[lane + 64*j] != 0) ? 1 : 0;
    #pragma unroll
    for (int o = 32; o; o >>= 1) cnt += __shfl_down(cnt, o, 64);
    if (lane == 0){ len[wid] = cnt; atomicAdd(&hist[cnt], 1); }
  } else if (b < NLB + NEB){                  // ---- embedding f32 -> f16
    int i = (b - NLB) * 256 + threadIdx.x;
    ef[i] = (_Float16)emb[i];
  } else if (b < NLB + NEB + 6){              // ---- pack w_hh (K=64: 2 frags)
    int tid = (b - NLB - NEB) * 256 + threadIdx.x;
    int f = tid >> 6, l = tid & 63;
    int jt = f >> 1, kf = f & 1;
    float sc = (jt < 8) ? SC_RZ : SC_N;       // exp2-arg scale folded in
    #pragma unroll
    for (int i = 0; i < 8; ++i){
      int row = jt * 16 + (l & 15);
      int col = kf * 32 + (l >> 4) * 8 + i;
      wpk[(size_t)tid * 8 + i] = (_Float16)(sc * whh[row * HS + col]);
    }
  } else {                                    // ---- pack w_ih (K=32: 1 frag)
    int tid = (b - NLB - NEB - 6) * 256 + threadIdx.x;
    int tile = tid >> 6, l = tid & 63;
    float sc = ((tile >> 2) < 2) ? SC_RZ : SC_N;
    #pragma unroll
    for (int i = 0; i < 8; ++i){
      int row = tile * 16 + (l & 15);
      int col = (l >> 4) * 8 + i;
      wpe[(size_t)tid * 8 + i] = (_Float16)(sc * wih[row * ES + col]);
    }
  }
}

// ---------------- K2: exclusive scan of hist[0..512] -> offs ----------------
__global__ __launch_bounds__(1024) void k_scan(const int* __restrict__ hist,
                                               int* __restrict__ offs){
  __shared__ int buf[1024];
  int i = threadIdx.x;
  buf[i] = (i < 513) ? hist[i] : 0;
  __syncthreads();
  for (int d = 1; d < 1024; d <<= 1){
    int v = (i >= d) ? buf[i - d] : 0;
    __syncthreads();
    buf[i] += v;
    __syncthreads();
  }
  if (i < 513) offs[i] = (i == 0) ? 0 : buf[i - 1];
}

// ---------------- K3: scatter seq ids sorted (ascending) by length ----------
__global__ __launch_bounds__(256) void k_scatter(const int* __restrict__ len,
                                                 int* __restrict__ offs,
                                                 int* __restrict__ perm){
  int i = blockIdx.x * 256 + threadIdx.x;
  int l = len[i];
  int pos = atomicAdd(&offs[l], 1);
  perm[pos] = i;
}

// ---------------- K4: recurrence -------------------------------------------
// As R7 (4-way u-split, serpentine balance, fused e-MFMA prefetch) plus:
// exp2-arg scales pre-folded into weights/biases (sig = rcp(1+exp2(D)),
// tanh = (1-t)*rcp(1+t) with no clamp — args bounded ~|6|, NaN needs <-44),
// and a select-free main loop for t < tmin (freeze only needed in the tail;
// sorted groups make tmin ~= tmax).
__global__ __launch_bounds__(256, 4) void k_gru(
    const int* __restrict__ x, const _Float16* __restrict__ ef,
    const _Float16* __restrict__ wpk, const _Float16* __restrict__ wpe,
    const float* __restrict__ bih, const float* __restrict__ bhh,
    const int* __restrict__ perm, const int* __restrict__ len,
    float* __restrict__ out)
{
  __shared__ __align__(16) _Float16 hb[2][16 * LDH];
  int qt   = threadIdx.x >> 6;
  int w = blockIdx.x >> 8, cq = blockIdx.x & 255;
  int rank = w * 256 + ((w & 1) ? (255 - cq) : cq);   // 0 = longest
  int grp  = 1023 - rank;                             // ascending-sorted index
  int lane = threadIdx.x & 63;
  int q = lane >> 4, c = lane & 15;
  int uu = qt*16 + c;

  v8h bfh[3][2], bfe[3];
  #pragma unroll
  for (int g = 0; g < 3; ++g){
    int tile = g*4 + qt;
    #pragma unroll
    for (int kf = 0; kf < 2; ++kf)
      bfh[g][kf] = *(const v8h*)(wpk + ((size_t)(tile*2 + kf)*64 + lane)*8);
    bfe[g] = *(const v8h*)(wpe + ((size_t)tile*64 + lane)*8);
  }

  int sq[4], ln[4];
  #pragma unroll
  for (int r = 0; r < 4; ++r){
    int s = perm[grp * 16 + q*4 + r];
    sq[r] = s;
    ln[r] = len[s];
  }
  // biases, pre-scaled to match the folded weights
  float br  = SC_RZ * (bih[uu]      + bhh[uu]);
  float bz  = SC_RZ * (bih[HS + uu] + bhh[HS + uu]);
  float ben = SC_N  *  bih[2*HS + uu];
  float bhn = SC_N  *  bhh[2*HS + uu];
  v4f brq  = {br, br, br, br};
  v4f bzq  = {bz, bz, bz, bz};
  v4f benq = {ben, ben, ben, ben};
  v4f bhnq = {bhn, bhn, bhn, bhn};

  float h[4];
  #pragma unroll
  for (int r = 0; r < 4; ++r) h[r] = 0.f;

  for (int i = threadIdx.x; i < 16*LDH; i += 256) hb[0][i] = (_Float16)0.f;
  __syncthreads();

  int tmax = max(max(ln[0], ln[1]), max(ln[2], ln[3]));
  tmax = max(tmax, __shfl_xor(tmax, 16, 64));
  tmax = max(tmax, __shfl_xor(tmax, 32, 64));
  int tmin = min(min(ln[0], ln[1]), min(ln[2], ln[3]));
  tmin = min(tmin, __shfl_xor(tmin, 16, 64));
  tmin = min(tmin, __shfl_xor(tmin, 32, 64));

  const int* xr = x + (size_t)perm[grp * 16 + c] * LSEQ;  // A-row m=c tokens

  v8h aec, aen;
  int tk1, tk2;
  v4f pra, prb, pza, pzb, dea, deb;   // e-partials: r, z, n (ping/pong)
  {
    int tk0 = xr[0];
    aec = *(const v8h*)(ef + (size_t)tk0 * ES + q*8);
    tk1 = xr[1];
    pra = __builtin_amdgcn_mfma_f32_16x16x32_f16(aec, bfe[0], brq,  0,0,0);
    pza = __builtin_amdgcn_mfma_f32_16x16x32_f16(aec, bfe[1], bzq,  0,0,0);
    dea = __builtin_amdgcn_mfma_f32_16x16x32_f16(aec, bfe[2], benq, 0,0,0);
  }

  // FREEZE is compile-time 0/1: main loop (0) skips the per-row length select.
  #define GRU_STEP(FREEZE, AEN, PRR, PRZ, DEN, PRRn, PRZn, DENn, TKN_, TKNN_, RB, WB) \
  {                                                                            \
    AEN = *(const v8h*)(ef + (size_t)TKN_ * ES + q*8);   /* emb frag t+1 */    \
    int t2 = min(t + 2, LSEQ - 1);                                             \
    TKNN_ = xr[t2];                                      /* token t+2 */       \
    v8h a0 = *(const v8h*)(&hb[RB][c*LDH + q*8]);                              \
    v8h a1 = *(const v8h*)(&hb[RB][c*LDH + 32 + q*8]);                         \
    v4f zr  = __builtin_amdgcn_mfma_f32_16x16x32_f16(a1, bfh[0][1], PRR, 0,0,0);\
    v4f Dr  = __builtin_amdgcn_mfma_f32_16x16x32_f16(a0, bfh[0][0], zr,  0,0,0);\
    v4f zz  = __builtin_amdgcn_mfma_f32_16x16x32_f16(a1, bfh[1][1], PRZ, 0,0,0);\
    v4f Dz  = __builtin_amdgcn_mfma_f32_16x16x32_f16(a0, bfh[1][0], zz,  0,0,0);\
    v4f zh  = __builtin_amdgcn_mfma_f32_16x16x32_f16(a1, bfh[2][1], bhnq,0,0,0);\
    v4f Dhn = __builtin_amdgcn_mfma_f32_16x16x32_f16(a0, bfh[2][0], zh,  0,0,0);\
    _Pragma("unroll")                                                          \
    for (int r = 0; r < 4; ++r){                                               \
      float rg   = __builtin_amdgcn_rcpf(1.f + __builtin_amdgcn_exp2f(Dr[r])); \
      float zg   = __builtin_amdgcn_rcpf(1.f + __builtin_amdgcn_exp2f(Dz[r])); \
      float te   = __builtin_amdgcn_exp2f(DEN[r] + rg * Dhn[r]);               \
      float ng   = (1.f - te) * __builtin_amdgcn_rcpf(1.f + te);               \
      float hnew = ng + zg * (h[r] - ng);                                      \
      h[r]       = (FREEZE && t >= ln[r]) ? h[r] : hnew;                       \
    }                                                                          \
    PRRn = __builtin_amdgcn_mfma_f32_16x16x32_f16(AEN, bfe[0], brq,  0,0,0);   \
    PRZn = __builtin_amdgcn_mfma_f32_16x16x32_f16(AEN, bfe[1], bzq,  0,0,0);   \
    DENn = __builtin_amdgcn_mfma_f32_16x16x32_f16(AEN, bfe[2], benq, 0,0,0);   \
    _Pragma("unroll")                                                          \
    for (int r = 0; r < 4; ++r)                                                \
      hb[WB][(q*4 + r)*LDH + uu] = (_Float16)h[r];                             \
    __syncthreads();                                                           \
  }

  int t = 0;
  for (; t + 1 < tmin; ){   // no-freeze main loop (t and t+1 both < all ln)
    GRU_STEP(0, aen, pra, pza, dea, prb, pzb, deb, tk1, tk2, 0, 1); ++t;
    GRU_STEP(0, aec, prb, pzb, deb, pra, pza, dea, tk2, tk1, 1, 0); ++t;
  }
  for (; t + 1 < tmax; ){   // tail pairs with freeze (parity preserved: t even)
    GRU_STEP(1, aen, pra, pza, dea, prb, pzb, deb, tk1, tk2, 0, 1); ++t;
    GRU_STEP(1, aec, prb, pzb, deb, pra, pza, dea, tk2, tk1, 1, 0); ++t;
  }
  if (t < tmax){
    GRU_STEP(1, aen, pra, pza, dea, prb, pzb, deb, tk1, tk2, 0, 1); ++t;
  }
  #undef GRU_STEP

  #pragma unroll
  for (int r = 0; r < 4; ++r)
    out[(size_t)sq[r] * HS + uu] = h[r];
}

extern "C" void kernel_launch(void* const* d_in, const int* in_sizes, int n_in,
                              void* d_out, int out_size, void* d_ws, size_t ws_size,
                              hipStream_t stream){
  const int*   x   = (const int*)  d_in[0];
  const float* emb = (const float*)d_in[1];
  const float* wih = (const float*)d_in[2];
  const float* whh = (const float*)d_in[3];
  const float* bih = (const float*)d_in[4];
  const float* bhh = (const float*)d_in[5];
  float* out = (float*)d_out;

  char* ws = (char*)d_ws;
  size_t off = 0;
  _Float16* ef  = (_Float16*)(ws + off);  off += (size_t)VOCAB * ES * sizeof(_Float16);
  _Float16* wpk = (_Float16*)(ws + off);  off += (size_t)24 * 64 * 8 * sizeof(_Float16);
  _Float16* wpe = (_Float16*)(ws + off);  off += (size_t)12 * 64 * 8 * sizeof(_Float16);
  off = (off + 255) & ~(size_t)255;
  int* len  = (int*)(ws + off);           off += (size_t)N_SEQ * sizeof(int);
  int* perm = (int*)(ws + off);           off += (size_t)N_SEQ * sizeof(int);
  int* hist = (int*)(ws + off);           off += 513 * sizeof(int);
  off = (off + 255) & ~(size_t)255;
  int* offs = (int*)(ws + off);           off += 513 * sizeof(int);

  hipMemsetAsync(hist, 0, 513 * sizeof(int), stream);
  k_prep   <<<NLB + NEB + 9, 256, 0, stream>>>(x, emb, whh, wih, len, hist, ef, wpk, wpe);
  k_scan   <<<1,            1024, 0, stream>>>(hist, offs);
  k_scatter<<<N_SEQ / 256,   256, 0, stream>>>(len, offs, perm);
  k_gru    <<<N_SEQ / 16,    256, 0, stream>>>(x, ef, wpk, wpe, bih, bhh, perm, len, out);
}